// Round 6
// baseline (2761.874 us; speedup 1.0000x reference)
//
#include <hip/hip_runtime.h>

// ---------------------------------------------------------------------------
// Swin-style transformer block, MI355X (gfx950).
// GEMMs: 128x256 tile, BK=64, 8 waves, single-buffer LDS (48KB -> 2 blocks/CU),
// 1 barrier per K-tile, stage(t+1) overlapped with MFMA, granule-XOR swizzle
// (verified 0 bank conflicts), XCD-aware bijective block swizzle, setprio.
// ---------------------------------------------------------------------------

typedef short short8 __attribute__((ext_vector_type(8)));
typedef unsigned short ushort8 __attribute__((ext_vector_type(8)));
typedef float floatx4 __attribute__((ext_vector_type(4)));

static constexpr int R_TOT = 73728;  // 8192 windows * 9 tokens

__device__ __forceinline__ unsigned short f2bf(float f) {
  union { float f; unsigned int u; } v; v.f = f;
  unsigned int r = v.u + 0x7FFFu + ((v.u >> 16) & 1u);
  return (unsigned short)(r >> 16);
}
__device__ __forceinline__ float bf2f(unsigned short u) {
  union { unsigned int u; float f; } v; v.u = ((unsigned int)u) << 16;
  return v.f;
}

__device__ __forceinline__ void gload_lds16(const void* g, void* l) {
  __builtin_amdgcn_global_load_lds(
      (const __attribute__((address_space(1))) unsigned int*)g,
      (__attribute__((address_space(3))) unsigned int*)l, 16, 0, 0);
}

#define FENCE asm volatile("" ::: "memory")
#define BAR do { FENCE; __builtin_amdgcn_s_barrier(); FENCE; } while (0)
#define WAITV0 asm volatile("s_waitcnt vmcnt(0)" ::: "memory")

// --------------------------- weight f32 -> bf16 ----------------------------
__global__ __launch_bounds__(256)
void cvt4(const float* __restrict__ in, unsigned short* __restrict__ out) {
  int i = (blockIdx.x * 256 + threadIdx.x) * 4;
  floatx4 v = *(const floatx4*)(in + i);
  union { unsigned short s[4]; unsigned long long u; } pk;
  pk.s[0] = f2bf(v[0]); pk.s[1] = f2bf(v[1]); pk.s[2] = f2bf(v[2]); pk.s[3] = f2bf(v[3]);
  *(unsigned long long*)(out + i) = pk.u;
}

// ------------------------------- LayerNorm ---------------------------------
__global__ __launch_bounds__(256)
void ln_bf16(const float* __restrict__ in, const float* __restrict__ g,
             const float* __restrict__ b, unsigned short* __restrict__ out) {
  const int lane = threadIdx.x & 63;
  const int wid = threadIdx.x >> 6;
  const size_t row = (size_t)blockIdx.x * 4 + wid;
  const float* p = in + row * 512 + lane * 8;
  floatx4 v0 = *(const floatx4*)p;
  floatx4 v1 = *(const floatx4*)(p + 4);
  float s = v0[0] + v0[1] + v0[2] + v0[3] + v1[0] + v1[1] + v1[2] + v1[3];
  float ss = v0[0]*v0[0] + v0[1]*v0[1] + v0[2]*v0[2] + v0[3]*v0[3]
           + v1[0]*v1[0] + v1[1]*v1[1] + v1[2]*v1[2] + v1[3]*v1[3];
  #pragma unroll
  for (int m = 1; m < 64; m <<= 1) { s += __shfl_xor(s, m); ss += __shfl_xor(ss, m); }
  float mu = s * (1.f / 512.f);
  float var = ss * (1.f / 512.f) - mu * mu;
  float rs = rsqrtf(var + 1e-5f);
  const float* gp = g + lane * 8;
  const float* bp = b + lane * 8;
  floatx4 g0 = *(const floatx4*)gp, g1 = *(const floatx4*)(gp + 4);
  floatx4 b0 = *(const floatx4*)bp, b1 = *(const floatx4*)(bp + 4);
  ushort8 o;
  o[0] = f2bf((v0[0] - mu) * rs * g0[0] + b0[0]);
  o[1] = f2bf((v0[1] - mu) * rs * g0[1] + b0[1]);
  o[2] = f2bf((v0[2] - mu) * rs * g0[2] + b0[2]);
  o[3] = f2bf((v0[3] - mu) * rs * g0[3] + b0[3]);
  o[4] = f2bf((v1[0] - mu) * rs * g1[0] + b1[0]);
  o[5] = f2bf((v1[1] - mu) * rs * g1[1] + b1[1]);
  o[6] = f2bf((v1[2] - mu) * rs * g1[2] + b1[2]);
  o[7] = f2bf((v1[3] - mu) * rs * g1[3] + b1[7-4]);
  *(ushort8*)(out + row * 512 + lane * 8) = o;
}

// --------------------- 128x256 GEMM (A @ W^T), BK=64 -----------------------
// A: (M x K) bf16 rm. Wp: (Nn x K) bf16 rm. Single LDS buffer:
// A[128][64] @0 (16KB), B[256][64] @16384 (32KB). Swizzle: LDS (row,kg)
// holds global kg^(row&7). 8 waves: wm=wid>>2 (64-row half), wn=wid&3
// (64-col quarter); wave-tile 64x64, acc[4][4].
template <int EPI>
__global__ __launch_bounds__(512, 4)
void gemmk(const unsigned short* __restrict__ Ap,
           const unsigned short* __restrict__ Wp,
           const float* __restrict__ bias,
           const float* __restrict__ resid,
           unsigned short* __restrict__ outb,
           float* __restrict__ outf,
           int K, int Nn, int ntn) {
  __shared__ __align__(16) char sm[49152];

  const int t = threadIdx.x;
  const int l = t & 63;
  const int wid = t >> 6;
  const int wm = wid >> 2;   // 0..1
  const int wn = wid & 3;    // 0..3

  // bijective XCD-aware swizzle (m204)
  const int nwg = gridDim.x;
  const int orig = blockIdx.x;
  const int q8 = nwg >> 3, r8 = nwg & 7;
  const int xcd = orig & 7, idx = orig >> 3;
  const int wg = (xcd < r8 ? xcd * (q8 + 1) : r8 * (q8 + 1) + (xcd - r8) * q8) + idx;
  const int tm = wg / ntn, tn = wg % ntn;
  const size_t rowB = (size_t)tm * 128;
  const size_t colB = (size_t)tn * 256;

  // staging: 8 rows per issue, 8 lanes/row; source k-granule pre-swizzled.
  const int srow = l >> 3;                       // row within 8-row issue
  const int sko = ((l & 7) ^ (l >> 3)) * 8;      // source k elements
  // reads: lane row = l&15, wanted kg = (l>>4) + kk*4, XOR (row&7)
  const int arow = l & 15;
  const int aoff0 = arow * 128 + (((l >> 4) + 0) ^ (arow & 7)) * 16;
  const int aoff1 = arow * 128 + (((l >> 4) + 4) ^ (arow & 7)) * 16;

  floatx4 acc[4][4];
  #pragma unroll
  for (int m = 0; m < 4; ++m)
    #pragma unroll
    for (int n = 0; n < 4; ++n)
      acc[m][n] = (floatx4){0.f, 0.f, 0.f, 0.f};

  const int NI = K >> 6;

  // prologue: stage tile 0 (A: 2 issues, B: 4 issues per wave)
  #pragma unroll
  for (int j = 0; j < 2; ++j)
    gload_lds16(Ap + (rowB + wid * 16 + j * 8 + srow) * (size_t)K + sko,
                sm + wid * 2048 + j * 1024);
  #pragma unroll
  for (int j = 0; j < 4; ++j)
    gload_lds16(Wp + (colB + wid * 32 + j * 8 + srow) * (size_t)K + sko,
                sm + 16384 + wid * 4096 + j * 1024);

  for (int kt = 0; kt < NI; ++kt) {
    WAITV0;   // own stage-writes landed
    BAR;      // everyone's landed; prev compute closed

    short8 aF[4][2], bF[4][2];
    #pragma unroll
    for (int mi = 0; mi < 4; ++mi) {
      aF[mi][0] = *(const short8*)(sm + wm * 8192 + mi * 2048 + aoff0);
      aF[mi][1] = *(const short8*)(sm + wm * 8192 + mi * 2048 + aoff1);
    }
    #pragma unroll
    for (int ni = 0; ni < 4; ++ni) {
      bF[ni][0] = *(const short8*)(sm + 16384 + wn * 8192 + ni * 2048 + aoff0);
      bF[ni][1] = *(const short8*)(sm + 16384 + wn * 8192 + ni * 2048 + aoff1);
    }

    // stage next tile (DMA lands >=hundreds of cycles later; all this tile's
    // ds_reads are already issued -- pattern validated rounds 3-4)
    if (kt + 1 < NI) {
      const int tk = (kt + 1) << 6;
      #pragma unroll
      for (int j = 0; j < 2; ++j)
        gload_lds16(Ap + (rowB + wid * 16 + j * 8 + srow) * (size_t)K + tk + sko,
                    sm + wid * 2048 + j * 1024);
      #pragma unroll
      for (int j = 0; j < 4; ++j)
        gload_lds16(Wp + (colB + wid * 32 + j * 8 + srow) * (size_t)K + tk + sko,
                    sm + 16384 + wid * 4096 + j * 1024);
    }

    __builtin_amdgcn_s_setprio(1);
    #pragma unroll
    for (int mi = 0; mi < 4; ++mi)
      #pragma unroll
      for (int ni = 0; ni < 4; ++ni) {
        acc[mi][ni] = __builtin_amdgcn_mfma_f32_16x16x32_bf16(aF[mi][0], bF[ni][0], acc[mi][ni], 0, 0, 0);
        acc[mi][ni] = __builtin_amdgcn_mfma_f32_16x16x32_bf16(aF[mi][1], bF[ni][1], acc[mi][ni], 0, 0, 0);
      }
    __builtin_amdgcn_s_setprio(0);
  }
  FENCE;

  // epilogue: wave-tile 64x64 at (rowB + wm*64, colB + wn*64)
  #pragma unroll
  for (int mi = 0; mi < 4; ++mi) {
    #pragma unroll
    for (int ni = 0; ni < 4; ++ni) {
      const int rr = (int)rowB + wm * 64 + mi * 16 + (l >> 4) * 4;
      const int cc = (int)colB + wn * 64 + ni * 16 + (l & 15);
      const float bs = bias[cc];
      #pragma unroll
      for (int j = 0; j < 4; ++j) {
        float v = acc[mi][ni][j] + bs;
        if (EPI == 1) v = 0.5f * v * (1.0f + erff(v * 0.70710678118654752f));
        if (EPI == 2) {
          v += resid[(size_t)(rr + j) * Nn + cc];
          outf[(size_t)(rr + j) * Nn + cc] = v;
        } else {
          outb[(size_t)(rr + j) * Nn + cc] = f2bf(v);
        }
      }
    }
  }
}

// -------------------------- window attention (9x9) -------------------------
__global__ __launch_bounds__(256)
void attn9(const unsigned short* __restrict__ qkv,
           const float* __restrict__ bias_table,
           unsigned short* __restrict__ out) {
  __shared__ float qL[4][9][64];
  __shared__ float kL[4][9][64];
  __shared__ float vL[4][9][64];
  __shared__ float sL[4][9][10];

  const int lane = threadIdx.x & 63;
  const int wid = threadIdx.x >> 6;
  const int bh = blockIdx.x * 4 + wid;
  const int b = bh >> 3;
  const int h = bh & 7;

  const size_t base = (size_t)b * 9 * 1536 + h * 64 + lane;
  #pragma unroll
  for (int i = 0; i < 9; ++i) {
    qL[wid][i][lane] = bf2f(qkv[base + i * 1536]) * 0.125f;
    kL[wid][i][lane] = bf2f(qkv[base + i * 1536 + 512]);
    vL[wid][i][lane] = bf2f(qkv[base + i * 1536 + 1024]);
  }
  __syncthreads();

  #pragma unroll
  for (int p = 0; p < 2; ++p) {
    int pair = lane + p * 64;
    if (pair < 81) {
      int i = pair / 9, j = pair % 9;
      const floatx4* qi = (const floatx4*)qL[wid][i];
      const floatx4* kj = (const floatx4*)kL[wid][j];
      float dot = 0.f;
      #pragma unroll
      for (int d = 0; d < 16; ++d) {
        floatx4 a = qi[d], c = kj[d];
        dot += a[0]*c[0] + a[1]*c[1] + a[2]*c[2] + a[3]*c[3];
      }
      int dy = i / 3 - j / 3 + 2;
      int dx = i % 3 - j % 3 + 2;
      dot += bias_table[(dy * 5 + dx) * 8 + h];
      sL[wid][i][j] = dot;
    }
  }
  __syncthreads();

  if (lane < 9) {
    float m = -1e30f;
    #pragma unroll
    for (int j = 0; j < 9; ++j) m = fmaxf(m, sL[wid][lane][j]);
    float e[9], sum = 0.f;
    #pragma unroll
    for (int j = 0; j < 9; ++j) { e[j] = __expf(sL[wid][lane][j] - m); sum += e[j]; }
    float inv = 1.f / sum;
    #pragma unroll
    for (int j = 0; j < 9; ++j) sL[wid][lane][j] = e[j] * inv;
  }
  __syncthreads();

  const size_t obase = (size_t)b * 9 * 512 + h * 64 + lane;
  #pragma unroll
  for (int i = 0; i < 9; ++i) {
    float a = 0.f;
    #pragma unroll
    for (int j = 0; j < 9; ++j) a += sL[wid][i][j] * vL[wid][j][lane];
    out[obase + i * 512] = f2bf(a);
  }
}

// -------------------- depthwise 3x3 merge conv (9 -> 1) --------------------
__global__ __launch_bounds__(256)
void dwconv9(const float* __restrict__ x2, const float* __restrict__ wc,
             const float* __restrict__ bc, float* __restrict__ out) {
  int idx = blockIdx.x * 256 + threadIdx.x;  // local: b*512 + c
  int c = idx & 511;
  int b = idx >> 9;
  const float* xp = x2 + (size_t)b * 9 * 512 + c;
  float acc = bc[c];
  #pragma unroll
  for (int t = 0; t < 9; ++t) acc += xp[t * 512] * wc[c * 9 + t];
  out[idx] = acc;
}

// ---------------------------------------------------------------------------
extern "C" void kernel_launch(void* const* d_in, const int* in_sizes, int n_in,
                              void* d_out, int out_size, void* d_ws, size_t ws_size,
                              hipStream_t stream) {
  const float* x      = (const float*)d_in[0];
  const float* gamma1 = (const float*)d_in[1];
  const float* beta1  = (const float*)d_in[2];
  const float* w_qkv  = (const float*)d_in[3];
  const float* b_qkv  = (const float*)d_in[4];
  const float* bias_t = (const float*)d_in[5];
  const float* w_proj = (const float*)d_in[6];
  const float* b_proj = (const float*)d_in[7];
  const float* gamma2 = (const float*)d_in[8];
  const float* beta2  = (const float*)d_in[9];
  const float* w_fc1  = (const float*)d_in[10];
  const float* b_fc1  = (const float*)d_in[11];
  const float* w_fc2  = (const float*)d_in[12];
  const float* b_fc2  = (const float*)d_in[13];
  const float* w_conv = (const float*)d_in[14];
  const float* b_conv = (const float*)d_in[15];
  float* out = (float*)d_out;

  // ---- adaptive chunking: need = 6.29MB + M_C*10240 bytes ----
  static const int cand[6] = {73728, 36864, 18432, 9216, 4608, 2304};
  int M_C = 2304;
  for (int i = 0; i < 6; ++i) {
    size_t need = 6291456ull + (size_t)cand[i] * 10240ull;
    if (need <= ws_size) { M_C = cand[i]; break; }
  }
  const int nChunks = R_TOT / M_C;
  const int winC = M_C / 9;

  char* ws = (char*)d_ws;
  unsigned short* wqkvb  = (unsigned short*)(ws);
  unsigned short* wprojb = (unsigned short*)(ws + 1572864);
  unsigned short* wfc1b  = (unsigned short*)(ws + 2097152);
  unsigned short* wfc2b  = (unsigned short*)(ws + 4194304);
  char* base = ws + 6291456;
  const size_t szHB  = (size_t)M_C * 1024;   // M_C*512 bf16
  const size_t szQKV = (size_t)M_C * 3072;   // M_C*1536 bf16
  const size_t szX1  = (size_t)M_C * 2048;   // M_C*512 f32
  unsigned short* hb   = (unsigned short*)base;                 // also aob
  unsigned short* aob  = hb;
  unsigned short* qkvb = (unsigned short*)(base + szHB);
  unsigned short* h2b  = qkvb;                                  // reuse
  float* x2            = (float*)(base + szHB + szHB);          // inside qkvb region
  float* x1            = (float*)(base + szHB + szQKV);
  unsigned short* gb   = (unsigned short*)(base + szHB + szQKV + szX1);

  // 1. weights -> bf16 (once)
  cvt4<<<768, 256, 0, stream>>>(w_qkv, wqkvb);
  cvt4<<<256, 256, 0, stream>>>(w_proj, wprojb);
  cvt4<<<1024, 256, 0, stream>>>(w_fc1, wfc1b);
  cvt4<<<1024, 256, 0, stream>>>(w_fc2, wfc2b);

  const int mt128 = M_C / 128;
  for (int ch = 0; ch < nChunks; ++ch) {
    const size_t rOff = (size_t)ch * M_C;
    const float* xC = x + rOff * 512;
    float* outC = out + (size_t)ch * winC * 512;

    ln_bf16<<<M_C / 4, 256, 0, stream>>>(xC, gamma1, beta1, hb);
    gemmk<0><<<dim3(mt128 * 6), 512, 0, stream>>>(hb, wqkvb, b_qkv, nullptr, qkvb, nullptr, 512, 1536, 6);
    attn9<<<winC * 2, 256, 0, stream>>>(qkvb, bias_t, aob);
    gemmk<2><<<dim3(mt128 * 2), 512, 0, stream>>>(aob, wprojb, b_proj, xC, nullptr, x1, 512, 512, 2);
    ln_bf16<<<M_C / 4, 256, 0, stream>>>(x1, gamma2, beta2, h2b);
    gemmk<1><<<dim3(mt128 * 8), 512, 0, stream>>>(h2b, wfc1b, b_fc1, nullptr, gb, nullptr, 512, 2048, 8);
    gemmk<2><<<dim3(mt128 * 2), 512, 0, stream>>>(gb, wfc2b, b_fc2, x1, nullptr, x2, 2048, 512, 2);
    dwconv9<<<winC * 2, 256, 0, stream>>>(x2, w_conv, b_conv, outC);
  }
}

// Round 10
// 1217.890 us; speedup vs baseline: 2.2678x; 2.2678x over previous
//
#include <hip/hip_runtime.h>

// ---------------------------------------------------------------------------
// Swin-style transformer block, MI355X (gfx950).
// Unified GEMM: 128x128 tile, BK=64, 4 waves, double-buffered LDS (64KB ->
// 2 blocks/CU), counted vmcnt(8), granule-XOR swizzle (0 conflicts, verified
// r4), lgkmcnt(0) before barrier (stage/read race-free), setprio, XCD swizzle.
// ---------------------------------------------------------------------------

typedef short short8 __attribute__((ext_vector_type(8)));
typedef unsigned short ushort8 __attribute__((ext_vector_type(8)));
typedef float floatx4 __attribute__((ext_vector_type(4)));

static constexpr int R_TOT = 73728;  // 8192 windows * 9 tokens

__device__ __forceinline__ unsigned short f2bf(float f) {
  union { float f; unsigned int u; } v; v.f = f;
  unsigned int r = v.u + 0x7FFFu + ((v.u >> 16) & 1u);
  return (unsigned short)(r >> 16);
}
__device__ __forceinline__ float bf2f(unsigned short u) {
  union { unsigned int u; float f; } v; v.u = ((unsigned int)u) << 16;
  return v.f;
}

__device__ __forceinline__ void gload_lds16(const void* g, void* l) {
  __builtin_amdgcn_global_load_lds(
      (const __attribute__((address_space(1))) unsigned int*)g,
      (__attribute__((address_space(3))) unsigned int*)l, 16, 0, 0);
}

#define FENCE asm volatile("" ::: "memory")
#define BAR do { FENCE; __builtin_amdgcn_s_barrier(); FENCE; } while (0)
#define WAITV0 asm volatile("s_waitcnt vmcnt(0)" ::: "memory")
#define WAITV8 asm volatile("s_waitcnt vmcnt(8)" ::: "memory")
#define WAITLG0 asm volatile("s_waitcnt lgkmcnt(0)" ::: "memory")

// --------------------------- weight f32 -> bf16 ----------------------------
__global__ __launch_bounds__(256)
void cvt4(const float* __restrict__ in, unsigned short* __restrict__ out) {
  int i = (blockIdx.x * 256 + threadIdx.x) * 4;
  floatx4 v = *(const floatx4*)(in + i);
  union { unsigned short s[4]; unsigned long long u; } pk;
  pk.s[0] = f2bf(v[0]); pk.s[1] = f2bf(v[1]); pk.s[2] = f2bf(v[2]); pk.s[3] = f2bf(v[3]);
  *(unsigned long long*)(out + i) = pk.u;
}

// ------------------------------- LayerNorm ---------------------------------
__global__ __launch_bounds__(256)
void ln_bf16(const float* __restrict__ in, const float* __restrict__ g,
             const float* __restrict__ b, unsigned short* __restrict__ out) {
  const int lane = threadIdx.x & 63;
  const int wid = threadIdx.x >> 6;
  const size_t row = (size_t)blockIdx.x * 4 + wid;
  const float* p = in + row * 512 + lane * 8;
  floatx4 v0 = *(const floatx4*)p;
  floatx4 v1 = *(const floatx4*)(p + 4);
  float s = v0[0] + v0[1] + v0[2] + v0[3] + v1[0] + v1[1] + v1[2] + v1[3];
  float ss = v0[0]*v0[0] + v0[1]*v0[1] + v0[2]*v0[2] + v0[3]*v0[3]
           + v1[0]*v1[0] + v1[1]*v1[1] + v1[2]*v1[2] + v1[3]*v1[3];
  #pragma unroll
  for (int m = 1; m < 64; m <<= 1) { s += __shfl_xor(s, m); ss += __shfl_xor(ss, m); }
  float mu = s * (1.f / 512.f);
  float var = ss * (1.f / 512.f) - mu * mu;
  float rs = rsqrtf(var + 1e-5f);
  const float* gp = g + lane * 8;
  const float* bp = b + lane * 8;
  floatx4 g0 = *(const floatx4*)gp, g1 = *(const floatx4*)(gp + 4);
  floatx4 b0 = *(const floatx4*)bp, b1 = *(const floatx4*)(bp + 4);
  ushort8 o;
  o[0] = f2bf((v0[0] - mu) * rs * g0[0] + b0[0]);
  o[1] = f2bf((v0[1] - mu) * rs * g0[1] + b0[1]);
  o[2] = f2bf((v0[2] - mu) * rs * g0[2] + b0[2]);
  o[3] = f2bf((v0[3] - mu) * rs * g0[3] + b0[3]);
  o[4] = f2bf((v1[0] - mu) * rs * g1[0] + b1[0]);
  o[5] = f2bf((v1[1] - mu) * rs * g1[1] + b1[1]);
  o[6] = f2bf((v1[2] - mu) * rs * g1[2] + b1[2]);
  o[7] = f2bf((v1[3] - mu) * rs * g1[3] + b1[3]);
  *(ushort8*)(out + row * 512 + lane * 8) = o;
}

// ------------------- 128x128 GEMM (A @ W^T), BK=64, dbuf -------------------
// A: (M x K) bf16 rm. Wp: (Nn x K) bf16 rm. Per buf: A[128][64] @0 (16KB),
// B[128][64] @16384 (16KB). LDS (row, kg16B) holds global kg^(row&7).
// 4 waves: wm=wid>>1, wn=wid&1; wave-tile 64x64, acc[4][4].

#define STAGE(buf, tk) do { \
  _Pragma("unroll") \
  for (int j = 0; j < 4; ++j) \
    gload_lds16(Ap + (rowB + (wid * 4 + j) * 8 + sro) * (size_t)K + (tk) + sko, \
                sm + (buf) * 32768 + (wid * 4 + j) * 1024); \
  _Pragma("unroll") \
  for (int j = 0; j < 4; ++j) \
    gload_lds16(Wp + (colB + (wid * 4 + j) * 8 + sro) * (size_t)K + (tk) + sko, \
                sm + (buf) * 32768 + 16384 + (wid * 4 + j) * 1024); \
} while (0)

template <int EPI>
__global__ __launch_bounds__(256, 2)
void gemmd(const unsigned short* __restrict__ Ap,
           const unsigned short* __restrict__ Wp,
           const float* __restrict__ bias,
           const float* __restrict__ resid,
           unsigned short* __restrict__ outb,
           float* __restrict__ outf,
           int K, int Nn, int ntn) {
  __shared__ __align__(16) char sm[65536];

  const int t = threadIdx.x;
  const int l = t & 63;
  const int wid = t >> 6;          // 0..3
  const int wm = wid >> 1;         // 0..1
  const int wn = wid & 1;          // 0..1

  // bijective XCD-aware swizzle (m204)
  const int nwg = gridDim.x;
  const int orig = blockIdx.x;
  const int q8 = nwg >> 3, r8 = nwg & 7;
  const int xcd = orig & 7, idx = orig >> 3;
  const int wg = (xcd < r8 ? xcd * (q8 + 1) : r8 * (q8 + 1) + (xcd - r8) * q8) + idx;
  const int tm = wg / ntn, tn = wg % ntn;
  const size_t rowB = (size_t)tm * 128;
  const size_t colB = (size_t)tn * 128;

  // staging: each wave-issue covers 8 rows x 64 k (1024 B); lane l -> row
  // +(l>>3), k-granule (l&7); source pre-swizzled by ^(row&7).
  const int sro = l >> 3;
  const int sko = ((l & 7) ^ sro) * 8;
  // reads: lane row = l&15; wanted kg = (l>>4) (+4 for hi half), XOR (row&7)
  const int arow = l & 15;
  const int aoff0 = arow * 128 + (((l >> 4) ^ (arow & 7)) * 16);
  const int aoff1 = arow * 128 + ((((l >> 4) + 4) ^ (arow & 7)) * 16);

  floatx4 acc[4][4];
  #pragma unroll
  for (int m = 0; m < 4; ++m)
    #pragma unroll
    for (int n = 0; n < 4; ++n)
      acc[m][n] = (floatx4){0.f, 0.f, 0.f, 0.f};

  const int NI = K >> 6;

  // prologue: stage tile 0 -> buf0, tile 1 -> buf1 (16 issues outstanding)
  STAGE(0, 0);
  STAGE(1, 64);

  for (int kt = 0; kt < NI; ++kt) {
    const int cur = kt & 1;
    if (kt + 1 < NI) { WAITV8; } else { WAITV0; }   // tile kt landed
    BAR;

    short8 aF[4][2], bF[4][2];
    #pragma unroll
    for (int mi = 0; mi < 4; ++mi) {
      aF[mi][0] = *(const short8*)(sm + cur * 32768 + wm * 8192 + mi * 2048 + aoff0);
      aF[mi][1] = *(const short8*)(sm + cur * 32768 + wm * 8192 + mi * 2048 + aoff1);
    }
    #pragma unroll
    for (int ni = 0; ni < 4; ++ni) {
      bF[ni][0] = *(const short8*)(sm + cur * 32768 + 16384 + wn * 8192 + ni * 2048 + aoff0);
      bF[ni][1] = *(const short8*)(sm + cur * 32768 + 16384 + wn * 8192 + ni * 2048 + aoff1);
    }
    WAITLG0;   // own reads complete -> buf may be overwritten after barrier
    BAR;

    if (kt + 2 < NI) STAGE(cur, (kt + 2) << 6);   // DMA overlaps MFMA below

    __builtin_amdgcn_s_setprio(1);
    #pragma unroll
    for (int mi = 0; mi < 4; ++mi)
      #pragma unroll
      for (int ni = 0; ni < 4; ++ni) {
        acc[mi][ni] = __builtin_amdgcn_mfma_f32_16x16x32_bf16(aF[mi][0], bF[ni][0], acc[mi][ni], 0, 0, 0);
        acc[mi][ni] = __builtin_amdgcn_mfma_f32_16x16x32_bf16(aF[mi][1], bF[ni][1], acc[mi][ni], 0, 0, 0);
      }
    __builtin_amdgcn_s_setprio(0);
  }
  FENCE;

  // epilogue: wave-tile 64x64 at (rowB + wm*64, colB + wn*64)
  #pragma unroll
  for (int mi = 0; mi < 4; ++mi) {
    #pragma unroll
    for (int ni = 0; ni < 4; ++ni) {
      const int rr = (int)rowB + wm * 64 + mi * 16 + (l >> 4) * 4;
      const int cc = (int)colB + wn * 64 + ni * 16 + (l & 15);
      const float bs = bias[cc];
      #pragma unroll
      for (int j = 0; j < 4; ++j) {
        float v = acc[mi][ni][j] + bs;
        if (EPI == 1) v = 0.5f * v * (1.0f + erff(v * 0.70710678118654752f));
        if (EPI == 2) {
          v += resid[(size_t)(rr + j) * Nn + cc];
          outf[(size_t)(rr + j) * Nn + cc] = v;
        } else {
          outb[(size_t)(rr + j) * Nn + cc] = f2bf(v);
        }
      }
    }
  }
}

// -------------------------- window attention (9x9) -------------------------
__global__ __launch_bounds__(256)
void attn9(const unsigned short* __restrict__ qkv,
           const float* __restrict__ bias_table,
           unsigned short* __restrict__ out) {
  __shared__ float qL[4][9][64];
  __shared__ float kL[4][9][64];
  __shared__ float vL[4][9][64];
  __shared__ float sL[4][9][10];

  const int lane = threadIdx.x & 63;
  const int wid = threadIdx.x >> 6;
  const int bh = blockIdx.x * 4 + wid;
  const int b = bh >> 3;
  const int h = bh & 7;

  const size_t base = (size_t)b * 9 * 1536 + h * 64 + lane;
  #pragma unroll
  for (int i = 0; i < 9; ++i) {
    qL[wid][i][lane] = bf2f(qkv[base + i * 1536]) * 0.125f;
    kL[wid][i][lane] = bf2f(qkv[base + i * 1536 + 512]);
    vL[wid][i][lane] = bf2f(qkv[base + i * 1536 + 1024]);
  }
  __syncthreads();

  #pragma unroll
  for (int p = 0; p < 2; ++p) {
    int pair = lane + p * 64;
    if (pair < 81) {
      int i = pair / 9, j = pair % 9;
      const floatx4* qi = (const floatx4*)qL[wid][i];
      const floatx4* kj = (const floatx4*)kL[wid][j];
      float dot = 0.f;
      #pragma unroll
      for (int d = 0; d < 16; ++d) {
        floatx4 a = qi[d], c = kj[d];
        dot += a[0]*c[0] + a[1]*c[1] + a[2]*c[2] + a[3]*c[3];
      }
      int dy = i / 3 - j / 3 + 2;
      int dx = i % 3 - j % 3 + 2;
      dot += bias_table[(dy * 5 + dx) * 8 + h];
      sL[wid][i][j] = dot;
    }
  }
  __syncthreads();

  if (lane < 9) {
    float m = -1e30f;
    #pragma unroll
    for (int j = 0; j < 9; ++j) m = fmaxf(m, sL[wid][lane][j]);
    float e[9], sum = 0.f;
    #pragma unroll
    for (int j = 0; j < 9; ++j) { e[j] = __expf(sL[wid][lane][j] - m); sum += e[j]; }
    float inv = 1.f / sum;
    #pragma unroll
    for (int j = 0; j < 9; ++j) sL[wid][lane][j] = e[j] * inv;
  }
  __syncthreads();

  const size_t obase = (size_t)b * 9 * 512 + h * 64 + lane;
  #pragma unroll
  for (int i = 0; i < 9; ++i) {
    float a = 0.f;
    #pragma unroll
    for (int j = 0; j < 9; ++j) a += sL[wid][i][j] * vL[wid][j][lane];
    out[obase + i * 512] = f2bf(a);
  }
}

// -------------------- depthwise 3x3 merge conv (9 -> 1) --------------------
__global__ __launch_bounds__(256)
void dwconv9(const float* __restrict__ x2, const float* __restrict__ wc,
             const float* __restrict__ bc, float* __restrict__ out) {
  int idx = blockIdx.x * 256 + threadIdx.x;  // local: b*512 + c
  int c = idx & 511;
  int b = idx >> 9;
  const float* xp = x2 + (size_t)b * 9 * 512 + c;
  float acc = bc[c];
  #pragma unroll
  for (int t = 0; t < 9; ++t) acc += xp[t * 512] * wc[c * 9 + t];
  out[idx] = acc;
}

// ---------------------------------------------------------------------------
extern "C" void kernel_launch(void* const* d_in, const int* in_sizes, int n_in,
                              void* d_out, int out_size, void* d_ws, size_t ws_size,
                              hipStream_t stream) {
  const float* x      = (const float*)d_in[0];
  const float* gamma1 = (const float*)d_in[1];
  const float* beta1  = (const float*)d_in[2];
  const float* w_qkv  = (const float*)d_in[3];
  const float* b_qkv  = (const float*)d_in[4];
  const float* bias_t = (const float*)d_in[5];
  const float* w_proj = (const float*)d_in[6];
  const float* b_proj = (const float*)d_in[7];
  const float* gamma2 = (const float*)d_in[8];
  const float* beta2  = (const float*)d_in[9];
  const float* w_fc1  = (const float*)d_in[10];
  const float* b_fc1  = (const float*)d_in[11];
  const float* w_fc2  = (const float*)d_in[12];
  const float* b_fc2  = (const float*)d_in[13];
  const float* w_conv = (const float*)d_in[14];
  const float* b_conv = (const float*)d_in[15];
  float* out = (float*)d_out;

  // ---- adaptive chunking: need = 6.29MB + M_C*10240 bytes ----
  static const int cand[6] = {73728, 36864, 18432, 9216, 4608, 2304};
  int M_C = 2304;
  for (int i = 0; i < 6; ++i) {
    size_t need = 6291456ull + (size_t)cand[i] * 10240ull;
    if (need <= ws_size) { M_C = cand[i]; break; }
  }
  const int nChunks = R_TOT / M_C;
  const int winC = M_C / 9;

  char* ws = (char*)d_ws;
  unsigned short* wqkvb  = (unsigned short*)(ws);
  unsigned short* wprojb = (unsigned short*)(ws + 1572864);
  unsigned short* wfc1b  = (unsigned short*)(ws + 2097152);
  unsigned short* wfc2b  = (unsigned short*)(ws + 4194304);
  char* base = ws + 6291456;
  const size_t szHB  = (size_t)M_C * 1024;   // M_C*512 bf16
  const size_t szQKV = (size_t)M_C * 3072;   // M_C*1536 bf16
  const size_t szX1  = (size_t)M_C * 2048;   // M_C*512 f32
  unsigned short* hb   = (unsigned short*)base;                 // also aob
  unsigned short* aob  = hb;
  unsigned short* qkvb = (unsigned short*)(base + szHB);
  unsigned short* h2b  = qkvb;                                  // reuse
  float* x2            = (float*)(base + szHB + szHB);          // inside qkvb region
  float* x1            = (float*)(base + szHB + szQKV);
  unsigned short* gb   = (unsigned short*)(base + szHB + szQKV + szX1);

  // 1. weights -> bf16 (once)
  cvt4<<<768, 256, 0, stream>>>(w_qkv, wqkvb);
  cvt4<<<256, 256, 0, stream>>>(w_proj, wprojb);
  cvt4<<<1024, 256, 0, stream>>>(w_fc1, wfc1b);
  cvt4<<<1024, 256, 0, stream>>>(w_fc2, wfc2b);

  const int mt128 = M_C / 128;
  for (int ch = 0; ch < nChunks; ++ch) {
    const size_t rOff = (size_t)ch * M_C;
    const float* xC = x + rOff * 512;
    float* outC = out + (size_t)ch * winC * 512;

    ln_bf16<<<M_C / 4, 256, 0, stream>>>(xC, gamma1, beta1, hb);
    gemmd<0><<<dim3(mt128 * 12), 256, 0, stream>>>(hb, wqkvb, b_qkv, nullptr, qkvb, nullptr, 512, 1536, 12);
    attn9<<<winC * 2, 256, 0, stream>>>(qkvb, bias_t, aob);
    gemmd<2><<<dim3(mt128 * 4), 256, 0, stream>>>(aob, wprojb, b_proj, xC, nullptr, x1, 512, 512, 4);
    ln_bf16<<<M_C / 4, 256, 0, stream>>>(x1, gamma2, beta2, h2b);
    gemmd<1><<<dim3(mt128 * 16), 256, 0, stream>>>(h2b, wfc1b, b_fc1, nullptr, gb, nullptr, 512, 2048, 16);
    gemmd<2><<<dim3(mt128 * 4), 256, 0, stream>>>(gb, wfc2b, b_fc2, x1, nullptr, x2, 2048, 512, 4);
    dwconv9<<<winC * 2, 256, 0, stream>>>(x2, w_conv, b_conv, outC);
  }
}